// Round 12
// baseline (29.619 us; speedup 1.0000x reference)
//
#include <hip/hip_runtime.h>
#include <hip/hip_bf16.h>

// out[b][c] = kxx_mean[b] + kyy[c] - 2*kxy_mean[b][c]
// x[32768][64] f32, atoms[64][32][64] f32, out[256][64] f32.
// R12 = R11 with ONE change: fexp2 uses __builtin_amdgcn_exp2f (compiler-
// visible v_exp_f32, MFMA->VALU hazards handled) instead of inline asm.
// R11's absmax 0.215 attributed to inline-asm read of MFMA dst without
// hazard wait-states (rule-18 class bug).

constexpr int   NODES = 128;
constexpr int   DD    = 64;
constexpr int   CC    = 64;
constexpr int   KK    = 32;
constexpr float GAMMA = 1.0f / 64.0f;
constexpr float LOG2E = 1.4426950408889634f;
constexpr float C1    = 2.0f * GAMMA * LOG2E;   // exp2-domain scale on S
constexpr float GL    = GAMMA * LOG2E;

typedef __attribute__((ext_vector_type(8)))  short short8;
typedef __attribute__((ext_vector_type(16))) float f32x16;

#define MFMA(a, b, c) __builtin_amdgcn_mfma_f32_32x32x16_bf16((a), (b), (c), 0, 0, 0)

__device__ __forceinline__ float fexp2(float x) {
#if __has_builtin(__builtin_amdgcn_exp2f)
    return __builtin_amdgcn_exp2f(x);
#else
    return exp2f(x);
#endif
}

__device__ __forceinline__ unsigned short f2bf(float f) {
    union { float f; unsigned int u; } a; a.f = f;
    unsigned int u = a.u;
    return (unsigned short)((u + 0x7FFFu + ((u >> 16) & 1u)) >> 16);  // RNE
}

// async global->LDS, 16B/lane; LDS dest wave-uniform base + lane*16.
__device__ __forceinline__ void gl16(const void* g, void* l) {
    __builtin_amdgcn_global_load_lds(
        (const __attribute__((address_space(1))) char*)g,
        (__attribute__((address_space(3))) char*)l, 16, 0, 0);
}

// ---------------------------------------------------------------------------
// prep: blocks 0..255 -> per-graph A-frags + norms; 256..319 -> per-atom
// B-frags (SCALED by C1) + can (raw -GL*||a||^2) + kyy. LDS union.
// A entry (validated r2-r10): lane l holds row (l&31), k = kt*16+(l>>5)*8+j,
// xfrag[b*1024 + (rt*4+kt)*64 + l]. B entry: lane l holds col (l&31), same k,
// bfrag[c*256 + kt*64 + l].
// ---------------------------------------------------------------------------
__global__ __launch_bounds__(256) void prep(const float* __restrict__ x,
                                            const float* __restrict__ atoms,
                                            short8* __restrict__ xfrag,
                                            float* __restrict__ nrm,
                                            short8* __restrict__ bfrag,
                                            float* __restrict__ can,
                                            float* __restrict__ kyy) {
    __shared__ float smem[NODES * (DD + 1)];   // 33280 B union
    const int bid = blockIdx.x, t = threadIdx.x;

    if (bid < 256) {   // ---- prep_x for graph b = bid ----
        const int b = bid;
        float (*a)[DD + 1] = (float(*)[DD + 1])smem;

        const float4* xg = reinterpret_cast<const float4*>(x + (size_t)b * NODES * DD);
        for (int i = t; i < NODES * DD / 4; i += 256) {
            const float4 v = xg[i];
            const int r = i >> 4, c4 = (i & 15) * 4;
            a[r][c4 + 0] = v.x; a[r][c4 + 1] = v.y;
            a[r][c4 + 2] = v.z; a[r][c4 + 3] = v.w;
        }
        __syncthreads();

        if (t < NODES) {
            float s = 0.f;
#pragma unroll
            for (int d = 0; d < DD; ++d) s = fmaf(a[t][d], a[t][d], s);
            nrm[b * NODES + t] = -GL * s;
        }
#pragma unroll
        for (int j = 0; j < 4; ++j) {
            const int e = t + 256 * j;            // (rt*4+kt)*64 + l
            const int l = e & 63, sl = e >> 6;
            const int row = (sl >> 2) * 32 + (l & 31);
            const int k0  = (sl & 3) * 16 + (l >> 5) * 8;
            short8 h;
#pragma unroll
            for (int q = 0; q < 8; ++q) h[q] = (short)f2bf(a[row][k0 + q]);
            xfrag[(size_t)b * 1024 + e] = h;
        }
    } else {           // ---- prep_atoms for atom c = bid - 256 ----
        const int c = bid - 256;
        float (*a)[DD + 1] = (float(*)[DD + 1])smem;        // uses [32][65]
        float* an   = smem + KK * (DD + 1);                 // 32 floats
        float* wred = an + KK;                              // 4 floats

        const float* ac = atoms + (size_t)c * KK * DD;
        for (int i = t; i < KK * DD; i += 256) a[i >> 6][i & 63] = ac[i];
        __syncthreads();

        if (t < KK) {
            float s = 0.f;
#pragma unroll
            for (int d = 0; d < DD; ++d) s = fmaf(a[t][d], a[t][d], s);
            an[t] = s;
            can[c * KK + t] = -GL * s;            // raw exponent constant
        }
        __syncthreads();

        {   // fragment emit (scaled by C1): wave wv = ktile wv
            const int wv = t >> 6, l = t & 63;
            const int kp = l & 31, khh = l >> 5;
            short8 h;
#pragma unroll
            for (int j = 0; j < 8; ++j)
                h[j] = (short)f2bf(C1 * a[kp][wv * 16 + khh * 8 + j]);
            bfrag[(size_t)c * 256 + wv * 64 + l] = h;
        }

        {   // kyy (exact f32)
            const int i = t >> 3, j0 = (t & 7) * 4;
            float s0 = 0, s1 = 0, s2 = 0, s3 = 0;
            for (int d = 0; d < DD; ++d) {
                const float aid = a[i][d];
                s0 = fmaf(aid, a[j0 + 0][d], s0);
                s1 = fmaf(aid, a[j0 + 1][d], s1);
                s2 = fmaf(aid, a[j0 + 2][d], s2);
                s3 = fmaf(aid, a[j0 + 3][d], s3);
            }
            const float ani = an[i];
            float s = fexp2(-GL * (ani + an[j0 + 0] - 2.f * s0))
                    + fexp2(-GL * (ani + an[j0 + 1] - 2.f * s1))
                    + fexp2(-GL * (ani + an[j0 + 2] - 2.f * s2))
                    + fexp2(-GL * (ani + an[j0 + 3] - 2.f * s3));
#pragma unroll
            for (int off = 32; off; off >>= 1) s += __shfl_xor(s, off);
            if ((t & 63) == 0) wred[t >> 6] = s;
        }
        __syncthreads();
        if (t == 0) kyy[c] = (wred[0] + wred[1] + wred[2] + wred[3]) * (1.0f / (KK * KK));
    }
}

// ---------------------------------------------------------------------------
// mmd_fused: grid 1024 = (b, cq), block 256 = 4 waves, wave w = rowtile w.
// 17 sub-phase slots g: g=0 kxx (Bx = x-frags of rowtile cq, unscaled),
// g=1..16 atoms cq*16+g-1 (B pre-scaled by C1). set = g>>2, slot = g&3,
// buf = set&1. Per set: stage next set (1 tile/wave, 4 gl16), compute 4
// sub-phases, 1 barrier. acc init = cx + ca -> epilogue = bare exp + sum.
// ---------------------------------------------------------------------------
__global__ __launch_bounds__(256, 4) void mmd_fused(const short8* __restrict__ xfrag,
                                                    const short8* __restrict__ bfrag,
                                                    const float* __restrict__ nrm,
                                                    const float* __restrict__ can,
                                                    float* __restrict__ kxxp,
                                                    float* __restrict__ sxyw) {
    const int bid = blockIdx.x, b = bid >> 2, cq = bid & 3;
    const int t = threadIdx.x, w = t >> 6, l = t & 63;
    const int l31 = l & 31, kh = l >> 5;

    __shared__ short8 Bb[2][4][256];      // 32 KB double-buffered tile sets
    __shared__ float  part16[4][17][16];  // 4.25 KB

    // A fragments for rowtile w (4 coalesced 16B loads)
    const short8* xa = xfrag + (size_t)b * 1024;
    short8 A[4];
#pragma unroll
    for (int kt = 0; kt < 4; ++kt) A[kt] = xa[(w * 4 + kt) * 64 + l];

    // cx: row-norm exponent constants for this wave's acc rows
    f32x16 cx;
    {
        const float* nb = nrm + b * NODES + w * 32 + 4 * kh;
#pragma unroll
        for (int q = 0; q < 4; ++q) {
            const float4 v = *reinterpret_cast<const float4*>(nb + 8 * q);
            cx[4*q+0] = v.x; cx[4*q+1] = v.y; cx[4*q+2] = v.z; cx[4*q+3] = v.w;
        }
    }
    // ca: per-atom column constants (this lane's col l31)
    float cav[16];
#pragma unroll
    for (int j = 0; j < 16; ++j) cav[j] = can[(cq * 16 + j) * KK + l31];

    const float ec0 = fexp2(nrm[b * NODES + cq * 32 + l31]);
    const short8* bq = bfrag + (size_t)(cq * 16) * 256;

    // prologue: stage set 0 (wave w stages tile g=w; g=0 is the kxx tile)
    {
        const short8* src = (w == 0) ? (xa + cq * 256) : (bq + (size_t)(w - 1) * 256);
#pragma unroll
        for (int q = 0; q < 4; ++q) gl16(src + q * 64 + l, &Bb[0][w][q * 64]);
    }
    __syncthreads();

#pragma unroll
    for (int s = 0; s < 5; ++s) {
        if (s < 4) {   // stage set s+1: wave w stages tile g = 4(s+1)+w
            const int g = 4 * (s + 1) + w;
            if (g <= 16) {
                const short8* src = bq + (size_t)(g - 1) * 256;
#pragma unroll
                for (int q = 0; q < 4; ++q)
                    gl16(src + q * 64 + l, &Bb[(s + 1) & 1][w][q * 64]);
            }
        }
#pragma unroll
        for (int p = 0; p < 4; ++p) {
            const int g = 4 * s + p;
            if (g <= 16) {
                short8 Bt[4];
#pragma unroll
                for (int kt = 0; kt < 4; ++kt) Bt[kt] = Bb[s & 1][p][kt * 64 + l];

                float ssum;
                if (g == 0) {   // kxx: unscaled Bx -> fmaf epilogue, *ec0
                    f32x16 acc = {};
#pragma unroll
                    for (int kt = 0; kt < 4; ++kt) acc = MFMA(A[kt], Bt[kt], acc);
                    float sa = 0.f, sb = 0.f;
#pragma unroll
                    for (int r = 0; r < 16; r += 2) {
                        sa += fexp2(fmaf(C1, acc[r],     cx[r]));
                        sb += fexp2(fmaf(C1, acc[r + 1], cx[r + 1]));
                    }
                    ssum = (sa + sb) * ec0;
                } else {        // atom: acc init = cx + ca; epilogue bare exp
                    f32x16 acc;
#pragma unroll
                    for (int r = 0; r < 16; ++r) acc[r] = cx[r] + cav[g - 1];
#pragma unroll
                    for (int kt = 0; kt < 4; ++kt) acc = MFMA(A[kt], Bt[kt], acc);
                    float sa = 0.f, sb = 0.f;
#pragma unroll
                    for (int r = 0; r < 16; r += 2) {
                        sa += fexp2(acc[r]);
                        sb += fexp2(acc[r + 1]);
                    }
                    ssum = sa + sb;
                }
                ssum += __shfl_xor(ssum, 32);
                ssum += __shfl_xor(ssum, 16);
                if (l < 16) part16[w][g][l] = ssum;
            }
        }
        __syncthreads();   // staged set landed + part writes visible
    }

    // ---- tail reduce ----
    {
        const int o = t >> 4, g = t & 15;     // o = atom 0..15 -> slot o+1
        float s = part16[0][o + 1][g] + part16[1][o + 1][g]
                + part16[2][o + 1][g] + part16[3][o + 1][g];
        s += __shfl_xor(s, 8);
        s += __shfl_xor(s, 4);
        s += __shfl_xor(s, 2);
        s += __shfl_xor(s, 1);
        if (g == 0) sxyw[b * CC + cq * 16 + o] = s;
    }
    if (t < 16) {
        float s = part16[0][0][t] + part16[1][0][t]
                + part16[2][0][t] + part16[3][0][t];
        s += __shfl_xor(s, 8);
        s += __shfl_xor(s, 4);
        s += __shfl_xor(s, 2);
        s += __shfl_xor(s, 1);
        if (t == 0) kxxp[b * 4 + cq] = s;
    }
}

// ---------------------------------------------------------------------------
// combine: out[b][c] = sum(kxxp[b])/16384 + kyy[c] - sxyw[b][c]/2048
// ---------------------------------------------------------------------------
__global__ __launch_bounds__(256) void combine(const float* __restrict__ kxxp,
                                               const float* __restrict__ kyy,
                                               const float* __restrict__ sxyw,
                                               float* __restrict__ out) {
    const int idx = blockIdx.x * 256 + threadIdx.x;
    const int b = idx >> 6, c = idx & 63;
    const float kxx = (kxxp[b * 4 + 0] + kxxp[b * 4 + 1] +
                       kxxp[b * 4 + 2] + kxxp[b * 4 + 3]) * (1.0f / 16384.0f);
    out[idx] = kxx + kyy[c] - sxyw[idx] * (1.0f / 2048.0f);
}

extern "C" void kernel_launch(void* const* d_in, const int* in_sizes, int n_in,
                              void* d_out, int out_size, void* d_ws, size_t ws_size,
                              hipStream_t stream) {
    const float* x     = (const float*)d_in[0];   // [32768, 64]
    const float* atoms = (const float*)d_in[1];   // [64, 32, 64]
    float* out = (float*)d_out;                   // [256, 64]

    char* ws = (char*)d_ws;
    short8* xfrag = (short8*)(ws);                        // 4 MiB
    short8* bfrag = (short8*)(ws + 4194304);              // 256 KiB
    float*  nrm   = (float*) (ws + 4456448);              // 128 KiB
    float*  can   = (float*) (ws + 4587520);              // 8 KiB
    float*  kyy   = (float*) (ws + 4595712);              // 256 B
    float*  kxxp  = (float*) (ws + 4595968);              // 4 KiB
    float*  sxyw  = (float*) (ws + 4600064);              // 64 KiB

    prep      <<<dim3(320),  dim3(256), 0, stream>>>(x, atoms, xfrag, nrm, bfrag, can, kyy);
    mmd_fused <<<dim3(1024), dim3(256), 0, stream>>>(xfrag, bfrag, nrm, can, kxxp, sxyw);
    combine   <<<dim3(CC),   dim3(256), 0, stream>>>(kxxp, kyy, sxyw, out);
}

// Round 13
// 29.366 us; speedup vs baseline: 1.0086x; 1.0086x over previous
//
#include <hip/hip_runtime.h>
#include <hip/hip_bf16.h>

// out[b][c] = kxx_mean[b] + kyy[c] - 2*kxy_mean[b][c]
// x[32768][64] f32, atoms[64][32][64] f32, out[256][64] f32.
// R13: TWO dispatches. prep_atoms (bfrag C1-scaled + can + kyy) and a
// self-sufficient fused kernel: in-block A-build from x, full-kxx per block
// (set 0, B = own A-frags via ds_write), 16 atoms (sets 1-4 via gl16 dbuf),
// direct out write. No xfrag / kxxp / sxyw / combine.

constexpr int   NODES = 128;
constexpr int   DD    = 64;
constexpr int   CC    = 64;
constexpr int   KK    = 32;
constexpr float GAMMA = 1.0f / 64.0f;
constexpr float LOG2E = 1.4426950408889634f;
constexpr float C1    = 2.0f * GAMMA * LOG2E;   // exp2-domain scale on S
constexpr float GL    = GAMMA * LOG2E;

typedef __attribute__((ext_vector_type(8)))  short short8;
typedef __attribute__((ext_vector_type(16))) float f32x16;

#define MFMA(a, b, c) __builtin_amdgcn_mfma_f32_32x32x16_bf16((a), (b), (c), 0, 0, 0)

__device__ __forceinline__ float fexp2(float x) {
#if __has_builtin(__builtin_amdgcn_exp2f)
    return __builtin_amdgcn_exp2f(x);   // compiler-visible: MFMA->VALU hazards handled
#else
    return exp2f(x);
#endif
}

__device__ __forceinline__ unsigned short f2bf(float f) {
    union { float f; unsigned int u; } a; a.f = f;
    unsigned int u = a.u;
    return (unsigned short)((u + 0x7FFFu + ((u >> 16) & 1u)) >> 16);  // RNE
}

// async global->LDS, 16B/lane; LDS dest wave-uniform base + lane*16.
__device__ __forceinline__ void gl16(const void* g, void* l) {
    __builtin_amdgcn_global_load_lds(
        (const __attribute__((address_space(1))) char*)g,
        (__attribute__((address_space(3))) char*)l, 16, 0, 0);
}

// ---------------------------------------------------------------------------
// prep_atoms: 64 blocks. B-frags SCALED by C1 (validated r12), can = raw
// -GL*||a||^2, kyy exact. B entry: lane l holds col (l&31), k=kt*16+(l>>5)*8+j,
// bfrag[c*256 + kt*64 + l].
// ---------------------------------------------------------------------------
__global__ __launch_bounds__(256) void prep_atoms(const float* __restrict__ atoms,
                                                  short8* __restrict__ bfrag,
                                                  float* __restrict__ can,
                                                  float* __restrict__ kyy) {
    const int c = blockIdx.x, t = threadIdx.x;
    __shared__ float a[KK][DD + 1];
    __shared__ float an[KK];
    __shared__ float wred[4];

    const float* ac = atoms + (size_t)c * KK * DD;
    for (int i = t; i < KK * DD; i += 256) a[i >> 6][i & 63] = ac[i];
    __syncthreads();

    if (t < KK) {
        float s = 0.f;
#pragma unroll
        for (int d = 0; d < DD; ++d) s = fmaf(a[t][d], a[t][d], s);
        an[t] = s;
        can[c * KK + t] = -GL * s;
    }
    __syncthreads();

    {   // fragment emit (scaled by C1): wave wv = ktile wv
        const int wv = t >> 6, l = t & 63;
        const int kp = l & 31, khh = l >> 5;
        short8 h;
#pragma unroll
        for (int j = 0; j < 8; ++j)
            h[j] = (short)f2bf(C1 * a[kp][wv * 16 + khh * 8 + j]);
        bfrag[(size_t)c * 256 + wv * 64 + l] = h;
    }

    {   // kyy (exact f32)
        const int i = t >> 3, j0 = (t & 7) * 4;
        float s0 = 0, s1 = 0, s2 = 0, s3 = 0;
        for (int d = 0; d < DD; ++d) {
            const float aid = a[i][d];
            s0 = fmaf(aid, a[j0 + 0][d], s0);
            s1 = fmaf(aid, a[j0 + 1][d], s1);
            s2 = fmaf(aid, a[j0 + 2][d], s2);
            s3 = fmaf(aid, a[j0 + 3][d], s3);
        }
        const float ani = an[i];
        float s = fexp2(-GL * (ani + an[j0 + 0] - 2.f * s0))
                + fexp2(-GL * (ani + an[j0 + 1] - 2.f * s1))
                + fexp2(-GL * (ani + an[j0 + 2] - 2.f * s2))
                + fexp2(-GL * (ani + an[j0 + 3] - 2.f * s3));
#pragma unroll
        for (int off = 32; off; off >>= 1) s += __shfl_xor(s, off);
        if ((t & 63) == 0) wred[t >> 6] = s;
    }
    __syncthreads();
    if (t == 0) kyy[c] = (wred[0] + wred[1] + wred[2] + wred[3]) * (1.0f / (KK * KK));
}

// ---------------------------------------------------------------------------
// mmd_fused: grid 1024 = (b, cq), block 256 = 4 waves, wave w = rowtile w.
// Prologue: build A[4] (bf16 frags, rowtile w) + exact norms from x;
// ds_write A -> Bb[0][w] (kxx B-tiles; A-layout == B-layout, validated r2+).
// 5 sets x 4 sub-phases: set 0 = kxx tiles (rt=w, ct=p), fmaf+ec0_p epilogue;
// sets 1-4 = atoms cq*16 + (s-1)*4+p, acc init = cx + ca, bare-exp epilogue.
// Stage set s+1 via gl16 during set s; 1 barrier/set. Direct out write.
// ---------------------------------------------------------------------------
__global__ __launch_bounds__(256, 4) void mmd_fused(const float* __restrict__ x,
                                                    const short8* __restrict__ bfrag,
                                                    const float* __restrict__ can,
                                                    const float* __restrict__ kyy,
                                                    float* __restrict__ out) {
    const int bid = blockIdx.x, b = bid >> 2, cq = bid & 3;
    const int t = threadIdx.x, w = t >> 6, l = t & 63;
    const int l31 = l & 31, kh = l >> 5;

    __shared__ short8 Bb[2][4][256];      // 32 KB double-buffered tile sets
    __shared__ float  part16[4][20][16];  // 5 KB partials
    __shared__ float  nl[NODES];          // 512 B: -GL*||x_row||^2
    __shared__ float  sxy_s[16];
    __shared__ float  kxx_s;

    // ---- A-build: rowtile w from x (strided, L3-hot; pattern validated r6) ----
    float v[32];
    {
        const float* xr = x + ((size_t)(b * NODES + w * 32 + l31)) * DD + kh * 8;
#pragma unroll
        for (int kt = 0; kt < 4; ++kt) {
            const float4 p0 = *reinterpret_cast<const float4*>(xr + kt * 16);
            const float4 p1 = *reinterpret_cast<const float4*>(xr + kt * 16 + 4);
            v[kt*8+0]=p0.x; v[kt*8+1]=p0.y; v[kt*8+2]=p0.z; v[kt*8+3]=p0.w;
            v[kt*8+4]=p1.x; v[kt*8+5]=p1.y; v[kt*8+6]=p1.z; v[kt*8+7]=p1.w;
        }
    }
    float xn = 0.f;
#pragma unroll
    for (int i = 0; i < 32; ++i) xn = fmaf(v[i], v[i], xn);
    xn += __shfl_xor(xn, 32);             // lane pair (l, l^32) = full row
    if (l < 32) nl[w * 32 + l] = -GL * xn;

    short8 A[4];
#pragma unroll
    for (int kt = 0; kt < 4; ++kt) {
        short8 h;
#pragma unroll
        for (int j = 0; j < 8; ++j) h[j] = (short)f2bf(v[kt * 8 + j]);
        A[kt] = h;
        Bb[0][w][kt * 64 + l] = h;        // set-0 kxx B-tile (own A frags)
    }

    // per-atom column constants for this lane's col l31
    float cav[16];
#pragma unroll
    for (int j = 0; j < 16; ++j) cav[j] = can[(cq * 16 + j) * KK + l31];

    __syncthreads();                      // nl + Bb[0] visible

    // cx: row-norm constants for this wave's acc rows (LDS float4 reads)
    f32x16 cx;
    {
        const float* nb = &nl[w * 32 + 4 * kh];
#pragma unroll
        for (int q = 0; q < 4; ++q) {
            const float4 vq = *reinterpret_cast<const float4*>(nb + 8 * q);
            cx[4*q+0] = vq.x; cx[4*q+1] = vq.y; cx[4*q+2] = vq.z; cx[4*q+3] = vq.w;
        }
    }

    const short8* bq = bfrag + (size_t)(cq * 16) * 256;

#pragma unroll
    for (int s = 0; s < 5; ++s) {
        if (s < 4) {   // stage set s+1: wave w stages quarter-atom s*4+w
            const short8* src = bq + (size_t)(s * 4 + w) * 256;
#pragma unroll
            for (int q = 0; q < 4; ++q)
                gl16(src + q * 64 + l, &Bb[(s + 1) & 1][w][q * 64]);
        }
#pragma unroll
        for (int p = 0; p < 4; ++p) {
            short8 Bt[4];
#pragma unroll
            for (int kt = 0; kt < 4; ++kt) Bt[kt] = Bb[s & 1][p][kt * 64 + l];

            float ssum;
            if (s == 0) {   // kxx tile (rt=w, ct=p): unscaled B -> fmaf, *ec0_p
                f32x16 acc = {};
#pragma unroll
                for (int kt = 0; kt < 4; ++kt) acc = MFMA(A[kt], Bt[kt], acc);
                const float ec0 = fexp2(nl[p * 32 + l31]);
                float sa = 0.f, sb = 0.f;
#pragma unroll
                for (int r = 0; r < 16; r += 2) {
                    sa += fexp2(fmaf(C1, acc[r],     cx[r]));
                    sb += fexp2(fmaf(C1, acc[r + 1], cx[r + 1]));
                }
                ssum = (sa + sb) * ec0;
            } else {        // atom (s-1)*4+p: acc init = cx + ca, bare exp
                const int j = (s - 1) * 4 + p;
                f32x16 acc;
#pragma unroll
                for (int r = 0; r < 16; ++r) acc[r] = cx[r] + cav[j];
#pragma unroll
                for (int kt = 0; kt < 4; ++kt) acc = MFMA(A[kt], Bt[kt], acc);
                float sa = 0.f, sb = 0.f;
#pragma unroll
                for (int r = 0; r < 16; r += 2) {
                    sa += fexp2(acc[r]);
                    sb += fexp2(acc[r + 1]);
                }
                ssum = sa + sb;
            }
            ssum += __shfl_xor(ssum, 32);
            ssum += __shfl_xor(ssum, 16);
            if (l < 16) part16[w][s * 4 + p][l] = ssum;
        }
        __syncthreads();   // staged set landed (vmcnt drain) + part writes
    }

    // ---- tail: reduce + direct out ----
    {
        const int o = t >> 4, g = t & 15;   // o = atom 0..15 (slot o+4)
        float s1 = part16[0][4 + o][g] + part16[1][4 + o][g]
                 + part16[2][4 + o][g] + part16[3][4 + o][g];
        s1 += __shfl_xor(s1, 8);
        s1 += __shfl_xor(s1, 4);
        s1 += __shfl_xor(s1, 2);
        s1 += __shfl_xor(s1, 1);
        if (g == 0) sxy_s[o] = s1;
    }
    if (t < 16) {
        float kx = 0.f;
#pragma unroll
        for (int ww = 0; ww < 4; ++ww)
#pragma unroll
            for (int q = 0; q < 4; ++q) kx += part16[ww][q][t];
        kx += __shfl_xor(kx, 8);
        kx += __shfl_xor(kx, 4);
        kx += __shfl_xor(kx, 2);
        kx += __shfl_xor(kx, 1);
        if (t == 0) kxx_s = kx;
    }
    __syncthreads();
    if (t < 16) {
        out[(size_t)b * CC + cq * 16 + t] =
            kxx_s * (1.0f / 16384.0f) + kyy[cq * 16 + t] - sxy_s[t] * (1.0f / 2048.0f);
    }
}

extern "C" void kernel_launch(void* const* d_in, const int* in_sizes, int n_in,
                              void* d_out, int out_size, void* d_ws, size_t ws_size,
                              hipStream_t stream) {
    const float* x     = (const float*)d_in[0];   // [32768, 64]
    const float* atoms = (const float*)d_in[1];   // [64, 32, 64]
    float* out = (float*)d_out;                   // [256, 64]

    char* ws = (char*)d_ws;
    short8* bfrag = (short8*)(ws);                        // 256 KiB
    float*  can   = (float*) (ws + 262144);               // 8 KiB
    float*  kyy   = (float*) (ws + 270336);               // 256 B

    prep_atoms<<<dim3(CC),   dim3(256), 0, stream>>>(atoms, bfrag, can, kyy);
    mmd_fused <<<dim3(1024), dim3(256), 0, stream>>>(x, bfrag, can, kyy, out);
}